// Round 17
// baseline (906.402 us; speedup 1.0000x reference)
//
#include <hip/hip_runtime.h>
#include <hip/hip_cooperative_groups.h>
#include <cstdint>
#include <cstddef>

#define CH 256      // all layers are 256-channel

namespace cg = cooperative_groups;

typedef _Float16 f16x8 __attribute__((ext_vector_type(8)));
typedef _Float16 f16x4 __attribute__((ext_vector_type(4)));
typedef float f32x4 __attribute__((ext_vector_type(4)));
typedef short short8 __attribute__((ext_vector_type(8)));

#define GLOB(x) ((const __attribute__((address_space(1))) void*)(x))
#define LDSP(x) ((__attribute__((address_space(3))) void*)(x))

// ---------------- helpers ----------------

__device__ __forceinline__ int ld_idx(const void* p, long long i, int w64) {
    if (w64) return (int)((const long long*)p)[i];
    return ((const int*)p)[i];
}

__device__ __forceinline__ float gelu_f(float x) {
    float x3 = x * x * x;
    float t = tanhf(0.7978845608028654f * (x + 0.044715f * x3));
    return 0.5f * x * (1.0f + t);
}

// ---------------- fused preprocessing (one cooperative launch) ----------------
// P0: zero deg/cnt; detect int64-vs-int32 layout; quantize x -> Xa,sxa; split W1..3 -> fp16^T
// P1: in-degree atomics         P2: per-256-chunk exclusive scan
// P3: scan of chunk partials    P4: rowptr offset add + dis
// P5: CSR scatter (src only)
// All math identical to the round-16 separate kernels; requires nb <= 256 (N <= 65536).

__global__ __launch_bounds__(256)
void k_prep(const void* __restrict__ ei, const float* __restrict__ x,
            const float* __restrict__ W1, const float* __restrict__ W2,
            const float* __restrict__ W3,
            int* __restrict__ flag, int* __restrict__ deg, int* __restrict__ cnt,
            int* __restrict__ rowptr, int* __restrict__ partial, float* __restrict__ dis,
            int* __restrict__ ssrc, uint8_t* __restrict__ Xa, float* __restrict__ sxa,
            _Float16* __restrict__ Wh1, _Float16* __restrict__ Wh2,
            _Float16* __restrict__ Wh3, int N, int E) {
    cg::grid_group grid = cg::this_grid();
    const int tid   = threadIdx.x;
    const int gsize = gridDim.x * 256;
    const int gid0  = blockIdx.x * 256 + tid;
    __shared__ int s[256];

    // ---- P0 ----
    if (blockIdx.x == 0 && tid < 64) {          // layout detect (64 samples)
        long long k = ((long long)tid * (long long)(E - 1)) / 63;
        int w = ((const int*)ei)[2 * k + 1];
        unsigned long long vote = __ballot(w == 0);
        if (tid == 0) *flag = (vote == ~0ULL) ? 1 : 0;
    }
    for (int i = gid0; i < N; i += gsize) { deg[i] = 0; cnt[i] = 0; }
    for (int i = gid0; i < 3 * CH * CH; i += gsize) {   // weight transpose+cast
        int l = i >> 16;                  // 65536 elems per layer
        int r = i & 65535;
        const float* W = (l == 0) ? W1 : (l == 1) ? W2 : W3;
        _Float16*   Wh = (l == 0) ? Wh1 : (l == 1) ? Wh2 : Wh3;
        Wh[r] = (_Float16)W[(r & 255) * CH + (r >> 8)];
    }
    {   // quantize x: one node per wave
        int wave = gid0 >> 6, lane = tid & 63;
        int nwaves = gsize >> 6;
        for (int node = wave; node < N; node += nwaves) {
            float4 v = ((const float4*)(x + (size_t)node * CH))[lane];
            float mx = fmaxf(fmaxf(fabsf(v.x), fabsf(v.y)), fmaxf(fabsf(v.z), fabsf(v.w)));
            #pragma unroll
            for (int off = 32; off > 0; off >>= 1)
                mx = fmaxf(mx, __shfl_xor(mx, off));
            float inv = (mx > 0.f) ? (32767.0f / mx) : 0.f;
            short4 q;
            q.x = (short)__float2int_rn(v.x * inv);
            q.y = (short)__float2int_rn(v.y * inv);
            q.z = (short)__float2int_rn(v.z * inv);
            q.w = (short)__float2int_rn(v.w * inv);
            *(short4*)(Xa + (size_t)node * 512 + (size_t)lane * 8) = q;
            if (lane == 0) sxa[node] = mx * (1.0f / 32767.0f);
        }
    }
    grid.sync();

    // ---- P1: in-degree ----
    int w64 = *flag;
    for (int e = gid0; e < E; e += gsize) {
        int d = ld_idx(ei, (long long)E + e, w64);
        atomicAdd(&deg[d], 1);
    }
    grid.sync();

    // ---- P2: per-chunk exclusive scans ----
    int nb = (N + 255) / 256;
    for (int b = blockIdx.x; b < nb; b += gridDim.x) {
        int g = b * 256 + tid;
        int v = (g < N) ? deg[g] : 0;
        s[tid] = v;
        __syncthreads();
        for (int off = 1; off < 256; off <<= 1) {
            int t = (tid >= off) ? s[tid - off] : 0;
            __syncthreads();
            s[tid] += t;
            __syncthreads();
        }
        if (g < N) rowptr[g] = s[tid] - v;
        if (tid == 255) partial[b] = s[255];
        __syncthreads();
    }
    grid.sync();

    // ---- P3: scan chunk partials (nb <= 256) ----
    if (blockIdx.x == 0) {
        int v = (tid < nb) ? partial[tid] : 0;
        s[tid] = v;
        __syncthreads();
        for (int off = 1; off < 256; off <<= 1) {
            int t = (tid >= off) ? s[tid - off] : 0;
            __syncthreads();
            s[tid] += t;
            __syncthreads();
        }
        if (tid < nb) partial[tid] = s[tid] - v;
    }
    grid.sync();

    // ---- P4: offsets + dis ----
    for (int i = gid0; i < N; i += gsize) {
        rowptr[i] += partial[i >> 8];
        dis[i] = 1.0f / sqrtf((float)(deg[i] + 1));
    }
    if (gid0 == 0) rowptr[N] = E;
    grid.sync();

    // ---- P5: scatter ----
    for (int e = gid0; e < E; e += gsize) {
        int sidx = ld_idx(ei, e, w64);
        int d = ld_idx(ei, (long long)E + e, w64);
        int pos = rowptr[d] + atomicAdd(&cnt[d], 1);
        ssrc[pos] = sidx;
    }
}

// ---------------- GEMM (int16 A as fp16, fp16 B, late scale fold) ----------------
// H16[M][512B] = quant16(s_row * (Aq @ Wh)); Wh fp16 transposed [c][k].
// comb-scale output: hcomb[node*2+half] = hscale * dis[node].
// Block: 128x128 output, 4 waves of 64x64, MFMA 16x16x32_f16, K-step 32.

#define GM 128
#define GN 128
#define GK 32

__global__ __launch_bounds__(256, 2)
void k_gemm16(const uint8_t* __restrict__ X16, const float* __restrict__ sx,
              const _Float16* __restrict__ Bh, const float* __restrict__ dis,
              uint8_t* __restrict__ H16, float* __restrict__ hcomb, int M) {
    __shared__ __align__(16) char smem[65536];
    short*    lA16 = (short*)smem;              // [2][128*32] int16 = 16 KB
    _Float16* lB   = (_Float16*)(smem + 16384); // [2][128*32] f16 = 16 KB

    const int tid  = threadIdx.x;
    const int lane = tid & 63;
    const int wid  = tid >> 6;
    const int m0   = blockIdx.x * GM;
    const int n0   = blockIdx.y * GN;
    const int wm   = wid >> 1, wn = wid & 1;
    const int r15  = lane & 15, kg = lane >> 4;

    auto stage = [&](int buf, int k0) {
        #pragma unroll
        for (int c = 0; c < 4; c++) {
            int call = wid * 4 + c;                 // wave-uniform 0..15
            int cc = call & 7;
            int L = cc * 64 + lane;                 // 0..511
            int row = L >> 2, ch = L & 3;
            int sch = ch ^ ((row >> 1) & 3);        // both-sides chunk swizzle
            if (call < 8) {                         // A int16: 128 rows x 4 chunks
                int gr = m0 + row; gr = (gr < M) ? gr : (M - 1);
                const uint8_t* g = X16 + (size_t)gr * 512 + (size_t)k0 * 2 + (sch << 4);
                __builtin_amdgcn_global_load_lds(GLOB(g), LDSP(&lA16[buf * 4096 + L * 8]), 16, 0, 0);
            } else {                                // B fp16: 128 rows x 4 chunks
                const _Float16* g = Bh + (size_t)(n0 + row) * CH + k0 + (sch << 3);
                __builtin_amdgcn_global_load_lds(GLOB(g), LDSP(&lB[buf * 4096 + L * 8]), 16, 0, 0);
            }
        }
    };

    f32x4 acc[4][4];
    #pragma unroll
    for (int i = 0; i < 4; i++)
        #pragma unroll
        for (int n = 0; n < 4; n++)
            acc[i][n] = (f32x4){0.f, 0.f, 0.f, 0.f};

    stage(0, 0);
    __syncthreads();

    for (int ks = 0; ks < 8; ks++) {
        int cur = ks & 1;
        if (ks < 7) stage(cur ^ 1, (ks + 1) * GK);

        f16x8 aq[4], bh[4];
        #pragma unroll
        for (int i = 0; i < 4; i++) {
            int R = wm * 64 + i * 16 + r15;
            int p = kg ^ ((R >> 1) & 3);
            short8 q = *(const short8*)&lA16[cur * 4096 + R * 32 + p * 8];
            #pragma unroll
            for (int j = 0; j < 8; j++)
                aq[i][j] = (_Float16)q[j];
        }
        #pragma unroll
        for (int n = 0; n < 4; n++) {
            int C = wn * 64 + n * 16 + r15;
            int p = kg ^ ((C >> 1) & 3);
            bh[n] = *(const f16x8*)&lB[cur * 4096 + C * GK + p * 8];
        }
        #pragma unroll
        for (int i = 0; i < 4; i++)
            #pragma unroll
            for (int n = 0; n < 4; n++)
                acc[i][n] = __builtin_amdgcn_mfma_f32_16x16x32_f16(aq[i], bh[n], acc[i][n], 0, 0, 0);
        __syncthreads();
    }

    // fold row-uniform input scale
    float sC[4][4];
    #pragma unroll
    for (int i = 0; i < 4; i++)
        #pragma unroll
        for (int r = 0; r < 4; r++) {
            int gr = m0 + wm * 64 + i * 16 + kg * 4 + r;
            sC[i][r] = sx[(gr < M) ? gr : (M - 1)];
        }
    #pragma unroll
    for (int i = 0; i < 4; i++)
        #pragma unroll
        for (int n = 0; n < 4; n++)
            #pragma unroll
            for (int r = 0; r < 4; r++)
                acc[i][n][r] *= sC[i][r];

    // epilogue: tile absmax -> scale, transpose via LDS, int16 store
    float mx = 0.f;
    #pragma unroll
    for (int i = 0; i < 4; i++)
        #pragma unroll
        for (int n = 0; n < 4; n++)
            #pragma unroll
            for (int r = 0; r < 4; r++)
                mx = fmaxf(mx, fabsf(acc[i][n][r]));
    #pragma unroll
    for (int off = 32; off > 0; off >>= 1)
        mx = fmaxf(mx, __shfl_xor(mx, off));
    if (lane == 0) ((float*)smem)[wid] = mx;
    __syncthreads();
    float tmax = fmaxf(fmaxf(((float*)smem)[0], ((float*)smem)[1]),
                       fmaxf(((float*)smem)[2], ((float*)smem)[3]));
    float scl = tmax * (1.0f / 32767.0f);
    float inv = (tmax > 0.f) ? (32767.0f / tmax) : 0.f;
    __syncthreads();

    float* ep = (float*)smem + wid * 4096;
    #pragma unroll
    for (int i = 0; i < 4; i++)
        #pragma unroll
        for (int n = 0; n < 4; n++)
            #pragma unroll
            for (int r = 0; r < 4; r++)
                ep[(i * 16 + kg * 4 + r) * 64 + n * 16 + r15] = acc[i][n][r];
    __syncthreads();

    int q = lane & 15;
    int rsub = lane >> 4;
    #pragma unroll
    for (int p = 0; p < 16; p++) {
        int lrow = p * 4 + rsub;
        int grow = m0 + wm * 64 + lrow;
        if (grow < M) {
            int q0 = __float2int_rn(ep[lrow * 64 + q * 4 + 0] * inv);
            int q1 = __float2int_rn(ep[lrow * 64 + q * 4 + 1] * inv);
            int q2 = __float2int_rn(ep[lrow * 64 + q * 4 + 2] * inv);
            int q3 = __float2int_rn(ep[lrow * 64 + q * 4 + 3] * inv);
            uint2 d;
            d.x = (q0 & 0xFFFF) | (q1 << 16);
            d.y = (q2 & 0xFFFF) | (q3 << 16);
            int col = n0 + wn * 64 + q * 4;
            *(uint2*)(H16 + (size_t)grow * 512 + (size_t)col * 2) = d;
        }
    }

    if (tid < GM && m0 + tid < M)
        hcomb[(size_t)(m0 + tid) * 2 + (n0 >> 7)] = scl * dis[m0 + tid];
}

// ---------------- sparse aggregation (gather-CSR over int16 H, src-only edges) --------
// out[n] = d * ( hcomb[n]*h[n] + sum_e hcomb[src_e]*h[src_e] ) + bias, d = dis[n]
// MODE 0: gelu -> per-node absmax -> int16 quantize to Xout + sxout (layers 1,2)
// MODE 1: fp32 store to out (layer 3, no gelu)

template <int MODE>
__global__ __launch_bounds__(256) void k_agg(const uint8_t* __restrict__ H16,
                                             const float* __restrict__ hcomb,
                                             const float* __restrict__ dis,
                                             const int* __restrict__ rowptr,
                                             const int* __restrict__ ssrc,
                                             const float* __restrict__ bias,
                                             float* __restrict__ out,
                                             uint8_t* __restrict__ Xout,
                                             float* __restrict__ sxout, int N) {
    int node = blockIdx.x * 4 + threadIdx.y;
    if (node >= N) return;
    int lane = threadIdx.x;  // 0..63
    int half = lane >> 5;
    float d = dis[node];
    short4 hv = *(const short4*)(H16 + (size_t)node * 512 + (size_t)lane * 8);
    float wself = d * hcomb[(size_t)node * 2 + half];   // dis^2 * hscale
    float ax = wself * (float)hv.x, ay = wself * (float)hv.y;
    float az = wself * (float)hv.z, aw = wself * (float)hv.w;
    int s = rowptr[node], e = rowptr[node + 1];
    int j = s;
    for (; j + 8 <= e; j += 8) {
        int p[8];
        #pragma unroll
        for (int t = 0; t < 8; t++) p[t] = ssrc[j + t];
        short4 v[8];
        float sc[8];
        #pragma unroll
        for (int t = 0; t < 8; t++) {
            v[t] = *(const short4*)(H16 + (size_t)p[t] * 512 + (size_t)lane * 8);
            sc[t] = hcomb[(size_t)p[t] * 2 + half];
        }
        #pragma unroll
        for (int t = 0; t < 8; t++) {
            float wn = d * sc[t];
            ax += wn * (float)v[t].x; ay += wn * (float)v[t].y;
            az += wn * (float)v[t].z; aw += wn * (float)v[t].w;
        }
    }
    for (; j < e; j++) {
        int p = ssrc[j];
        float wn = d * hcomb[(size_t)p * 2 + half];
        short4 v = *(const short4*)(H16 + (size_t)p * 512 + (size_t)lane * 8);
        ax += wn * (float)v.x; ay += wn * (float)v.y;
        az += wn * (float)v.z; aw += wn * (float)v.w;
    }
    float4 b = ((const float4*)bias)[lane];
    ax += b.x; ay += b.y; az += b.z; aw += b.w;
    if (MODE == 0) {
        ax = gelu_f(ax); ay = gelu_f(ay); az = gelu_f(az); aw = gelu_f(aw);
        float mx = fmaxf(fmaxf(fabsf(ax), fabsf(ay)), fmaxf(fabsf(az), fabsf(aw)));
        #pragma unroll
        for (int off = 32; off > 0; off >>= 1)
            mx = fmaxf(mx, __shfl_xor(mx, off));
        float inv = (mx > 0.f) ? (32767.0f / mx) : 0.f;
        short4 q;
        q.x = (short)__float2int_rn(ax * inv);
        q.y = (short)__float2int_rn(ay * inv);
        q.z = (short)__float2int_rn(az * inv);
        q.w = (short)__float2int_rn(aw * inv);
        *(short4*)(Xout + (size_t)node * 512 + (size_t)lane * 8) = q;
        if (lane == 0) sxout[node] = mx * (1.0f / 32767.0f);
    } else {
        ((float4*)(out + (size_t)node * CH))[lane] = make_float4(ax, ay, az, aw);
    }
}

// ---------------- launcher ----------------

extern "C" void kernel_launch(void* const* d_in, const int* in_sizes, int n_in,
                              void* d_out, int out_size, void* d_ws, size_t ws_size,
                              hipStream_t stream) {
    const void*  ei = d_in[1];
    const float* x  = (const float*)d_in[0];
    const float* W1 = (const float*)d_in[3]; const float* b1 = (const float*)d_in[4];
    const float* W2 = (const float*)d_in[5]; const float* b2 = (const float*)d_in[6];
    const float* W3 = (const float*)d_in[7]; const float* b3 = (const float*)d_in[8];

    int N = in_sizes[0] / CH;
    int E = in_sizes[1] / 2;
    float* out = (float*)d_out;

    char* ws = (char*)d_ws;
    auto take = [&](size_t bytes) {
        char* p = ws;
        ws += (bytes + 15) & ~(size_t)15;
        return p;
    };
    uint8_t*  H16    = (uint8_t*) take((size_t)N * 512);
    uint8_t*  Xa     = (uint8_t*) take((size_t)N * 512);
    uint8_t*  Xb     = (uint8_t*) take((size_t)N * 512);
    float*    hcomb  = (float*)   take((size_t)N * 2 * sizeof(float));
    float*    sxa    = (float*)   take((size_t)N * sizeof(float));
    float*    sxb    = (float*)   take((size_t)N * sizeof(float));
    int*      deg    = (int*)     take((size_t)N * sizeof(int));
    float*    dis    = (float*)   take((size_t)N * sizeof(float));
    int*      rowptr = (int*)     take((size_t)(N + 1) * sizeof(int));
    int*      cnt    = (int*)     take((size_t)N * sizeof(int));
    int*      part   = (int*)     take(4096);
    int*      flag   = (int*)     take(16);
    int*      ssrc   = (int*)     take((size_t)E * sizeof(int));
    _Float16* Wh1    = (_Float16*)take((size_t)CH * CH * 2);
    _Float16* Wh2    = (_Float16*)take((size_t)CH * CH * 2);
    _Float16* Wh3    = (_Float16*)take((size_t)CH * CH * 2);

    // fused preprocessing: one cooperative launch (1024 blocks x 256 = 4 blocks/CU)
    {
        void* pargs[] = {(void*)&ei, (void*)&x, (void*)&W1, (void*)&W2, (void*)&W3,
                         (void*)&flag, (void*)&deg, (void*)&cnt, (void*)&rowptr,
                         (void*)&part, (void*)&dis, (void*)&ssrc, (void*)&Xa,
                         (void*)&sxa, (void*)&Wh1, (void*)&Wh2, (void*)&Wh3,
                         (void*)&N, (void*)&E};
        hipLaunchCooperativeKernel((void*)k_prep, dim3(1024), dim3(256), pargs, 0, stream);
    }

    dim3 ggrid((N + GM - 1) / GM, CH / GN);
    dim3 agrid((N + 3) / 4);
    dim3 ablock(64, 4);

    // layer 1: Xa -> H16 -> Xb
    k_gemm16<<<ggrid, 256, 0, stream>>>(Xa, sxa, Wh1, dis, H16, hcomb, N);
    k_agg<0><<<agrid, ablock, 0, stream>>>(H16, hcomb, dis, rowptr, ssrc, b1, out, Xb, sxb, N);
    // layer 2: Xb -> H16 -> Xa
    k_gemm16<<<ggrid, 256, 0, stream>>>(Xb, sxb, Wh2, dis, H16, hcomb, N);
    k_agg<0><<<agrid, ablock, 0, stream>>>(H16, hcomb, dis, rowptr, ssrc, b2, out, Xa, sxa, N);
    // layer 3: Xa -> H16 -> out (fp32, no gelu)
    k_gemm16<<<ggrid, 256, 0, stream>>>(Xa, sxa, Wh3, dis, H16, hcomb, N);
    k_agg<1><<<agrid, ablock, 0, stream>>>(H16, hcomb, dis, rowptr, ssrc, b3, out, Xb, sxb, N);
}

// Round 18
// 373.107 us; speedup vs baseline: 2.4293x; 2.4293x over previous
//
#include <hip/hip_runtime.h>
#include <cstdint>
#include <cstddef>

#define CH 256      // all layers are 256-channel

typedef _Float16 f16x8 __attribute__((ext_vector_type(8)));
typedef _Float16 f16x4 __attribute__((ext_vector_type(4)));
typedef float f32x4 __attribute__((ext_vector_type(4)));
typedef short short8 __attribute__((ext_vector_type(8)));

#define GLOB(x) ((const __attribute__((address_space(1))) void*)(x))
#define LDSP(x) ((__attribute__((address_space(3))) void*)(x))

// ---------------- helpers ----------------

__device__ __forceinline__ int ld_idx(const void* p, long long i, int w64) {
    if (w64) return (int)((const long long*)p)[i];
    return ((const int*)p)[i];
}

__device__ __forceinline__ float gelu_f(float x) {
    float x3 = x * x * x;
    float t = tanhf(0.7978845608028654f * (x + 0.044715f * x3));
    return 0.5f * x * (1.0f + t);
}

// per-block int64-vs-int32 layout detect (64 samples, L2-hot, deterministic)
__device__ __forceinline__ int detect_w64(const void* ei, int E, int* sflag) {
    int tid = threadIdx.x;
    if (tid < 64) {
        long long k = ((long long)tid * (long long)(E - 1)) / 63;
        int w = ((const int*)ei)[2 * k + 1];
        unsigned long long vote = __ballot(w == 0);
        if (tid == 0) *sflag = (vote == ~0ULL) ? 1 : 0;
    }
    __syncthreads();
    return *sflag;
}

// ---------------- fused independent preprocessing (no cross-phase deps) ----------------
// zero deg/cnt + weight transpose/cast + input quantize. Stream ordering (not
// intra-kernel sync) guarantees deg=0 before k_deg's atomics.

__global__ __launch_bounds__(256)
void k_pre(const float* __restrict__ x,
           const float* __restrict__ W1, const float* __restrict__ W2,
           const float* __restrict__ W3,
           int* __restrict__ deg, int* __restrict__ cnt,
           uint8_t* __restrict__ Xa, float* __restrict__ sxa,
           _Float16* __restrict__ Wh1, _Float16* __restrict__ Wh2,
           _Float16* __restrict__ Wh3, int N) {
    const int tid   = threadIdx.x;
    const int gsize = gridDim.x * 256;
    const int gid0  = blockIdx.x * 256 + tid;

    for (int i = gid0; i < N; i += gsize) { deg[i] = 0; cnt[i] = 0; }

    for (int i = gid0; i < 3 * CH * CH; i += gsize) {   // weight transpose+cast
        int l = i >> 16;
        int r = i & 65535;
        const float* W = (l == 0) ? W1 : (l == 1) ? W2 : W3;
        _Float16*   Wh = (l == 0) ? Wh1 : (l == 1) ? Wh2 : Wh3;
        Wh[r] = (_Float16)W[(r & 255) * CH + (r >> 8)];
    }

    // quantize x: one node per wave
    int wave = gid0 >> 6, lane = tid & 63;
    int nwaves = gsize >> 6;
    for (int node = wave; node < N; node += nwaves) {
        float4 v = ((const float4*)(x + (size_t)node * CH))[lane];
        float mx = fmaxf(fmaxf(fabsf(v.x), fabsf(v.y)), fmaxf(fabsf(v.z), fabsf(v.w)));
        #pragma unroll
        for (int off = 32; off > 0; off >>= 1)
            mx = fmaxf(mx, __shfl_xor(mx, off));
        float inv = (mx > 0.f) ? (32767.0f / mx) : 0.f;
        short4 q;
        q.x = (short)__float2int_rn(v.x * inv);
        q.y = (short)__float2int_rn(v.y * inv);
        q.z = (short)__float2int_rn(v.z * inv);
        q.w = (short)__float2int_rn(v.w * inv);
        *(short4*)(Xa + (size_t)node * 512 + (size_t)lane * 8) = q;
        if (lane == 0) sxa[node] = mx * (1.0f / 32767.0f);
    }
}

// ---------------- graph preprocessing ----------------

__global__ void k_deg(const void* __restrict__ ei, int* __restrict__ deg, int E) {
    __shared__ int sflag;
    int w64 = detect_w64(ei, E, &sflag);
    int e = blockIdx.x * blockDim.x + threadIdx.x;
    if (e >= E) return;
    int d = ld_idx(ei, (long long)E + e, w64);
    atomicAdd(&deg[d], 1);
}

__global__ void k_scan_block(const int* __restrict__ deg, int* __restrict__ rowptr,
                             int* __restrict__ partial, int N) {
    __shared__ int s[256];
    int gid = blockIdx.x * 256 + threadIdx.x;
    int v = (gid < N) ? deg[gid] : 0;
    s[threadIdx.x] = v;
    __syncthreads();
    for (int off = 1; off < 256; off <<= 1) {
        int t = (threadIdx.x >= off) ? s[threadIdx.x - off] : 0;
        __syncthreads();
        s[threadIdx.x] += t;
        __syncthreads();
    }
    if (gid < N) rowptr[gid] = s[threadIdx.x] - v;
    if (threadIdx.x == 255) partial[blockIdx.x] = s[255];
}

__global__ void k_scan_partial(int* __restrict__ partial, int nb) {
    __shared__ int s[256];
    int i = threadIdx.x;
    int v = (i < nb) ? partial[i] : 0;
    s[i] = v;
    __syncthreads();
    for (int off = 1; off < 256; off <<= 1) {
        int t = (i >= off) ? s[i - off] : 0;
        __syncthreads();
        s[i] += t;
        __syncthreads();
    }
    if (i < nb) partial[i] = s[i] - v;
}

// fused: rowptr offset add + dis computation
__global__ void k_add_off(int* __restrict__ rowptr, const int* __restrict__ partial,
                          const int* __restrict__ deg, float* __restrict__ dis,
                          int N, int E) {
    int gid = blockIdx.x * 256 + threadIdx.x;
    if (gid < N) {
        rowptr[gid] += partial[blockIdx.x];
        dis[gid] = 1.0f / sqrtf((float)(deg[gid] + 1));
    }
    if (gid == 0) rowptr[N] = E;
}

// src-only scatter
__global__ void k_scatter(const void* __restrict__ ei, const int* __restrict__ rowptr,
                          int* __restrict__ cnt, int* __restrict__ ssrc, int E) {
    __shared__ int sflag;
    int w64 = detect_w64(ei, E, &sflag);
    int e = blockIdx.x * blockDim.x + threadIdx.x;
    if (e >= E) return;
    int s = ld_idx(ei, e, w64);
    int d = ld_idx(ei, (long long)E + e, w64);
    int pos = rowptr[d] + atomicAdd(&cnt[d], 1);
    ssrc[pos] = s;
}

// ---------------- GEMM (int16 A as fp16, fp16 B, late scale fold) ----------------
// H16[M][512B] = quant16(s_row * (Aq @ Wh)); Wh fp16 transposed [c][k].
// hcomb[node*2+half] = hscale * dis[node].
// Block: 128x128 output, 4 waves of 64x64, MFMA 16x16x32_f16, K-step 32.

#define GM 128
#define GN 128
#define GK 32

__global__ __launch_bounds__(256, 2)
void k_gemm16(const uint8_t* __restrict__ X16, const float* __restrict__ sx,
              const _Float16* __restrict__ Bh, const float* __restrict__ dis,
              uint8_t* __restrict__ H16, float* __restrict__ hcomb, int M) {
    __shared__ __align__(16) char smem[65536];
    short*    lA16 = (short*)smem;              // [2][128*32] int16 = 16 KB
    _Float16* lB   = (_Float16*)(smem + 16384); // [2][128*32] f16 = 16 KB

    const int tid  = threadIdx.x;
    const int lane = tid & 63;
    const int wid  = tid >> 6;
    const int m0   = blockIdx.x * GM;
    const int n0   = blockIdx.y * GN;
    const int wm   = wid >> 1, wn = wid & 1;
    const int r15  = lane & 15, kg = lane >> 4;

    auto stage = [&](int buf, int k0) {
        #pragma unroll
        for (int c = 0; c < 4; c++) {
            int call = wid * 4 + c;                 // wave-uniform 0..15
            int cc = call & 7;
            int L = cc * 64 + lane;                 // 0..511
            int row = L >> 2, ch = L & 3;
            int sch = ch ^ ((row >> 1) & 3);        // both-sides chunk swizzle
            if (call < 8) {                         // A int16: 128 rows x 4 chunks
                int gr = m0 + row; gr = (gr < M) ? gr : (M - 1);
                const uint8_t* g = X16 + (size_t)gr * 512 + (size_t)k0 * 2 + (sch << 4);
                __builtin_amdgcn_global_load_lds(GLOB(g), LDSP(&lA16[buf * 4096 + L * 8]), 16, 0, 0);
            } else {                                // B fp16: 128 rows x 4 chunks
                const _Float16* g = Bh + (size_t)(n0 + row) * CH + k0 + (sch << 3);
                __builtin_amdgcn_global_load_lds(GLOB(g), LDSP(&lB[buf * 4096 + L * 8]), 16, 0, 0);
            }
        }
    };

    f32x4 acc[4][4];
    #pragma unroll
    for (int i = 0; i < 4; i++)
        #pragma unroll
        for (int n = 0; n < 4; n++)
            acc[i][n] = (f32x4){0.f, 0.f, 0.f, 0.f};

    stage(0, 0);
    __syncthreads();

    for (int ks = 0; ks < 8; ks++) {
        int cur = ks & 1;
        if (ks < 7) stage(cur ^ 1, (ks + 1) * GK);

        f16x8 aq[4], bh[4];
        #pragma unroll
        for (int i = 0; i < 4; i++) {
            int R = wm * 64 + i * 16 + r15;
            int p = kg ^ ((R >> 1) & 3);
            short8 q = *(const short8*)&lA16[cur * 4096 + R * 32 + p * 8];
            #pragma unroll
            for (int j = 0; j < 8; j++)
                aq[i][j] = (_Float16)q[j];
        }
        #pragma unroll
        for (int n = 0; n < 4; n++) {
            int C = wn * 64 + n * 16 + r15;
            int p = kg ^ ((C >> 1) & 3);
            bh[n] = *(const f16x8*)&lB[cur * 4096 + C * GK + p * 8];
        }
        #pragma unroll
        for (int i = 0; i < 4; i++)
            #pragma unroll
            for (int n = 0; n < 4; n++)
                acc[i][n] = __builtin_amdgcn_mfma_f32_16x16x32_f16(aq[i], bh[n], acc[i][n], 0, 0, 0);
        __syncthreads();
    }

    // fold row-uniform input scale
    float sC[4][4];
    #pragma unroll
    for (int i = 0; i < 4; i++)
        #pragma unroll
        for (int r = 0; r < 4; r++) {
            int gr = m0 + wm * 64 + i * 16 + kg * 4 + r;
            sC[i][r] = sx[(gr < M) ? gr : (M - 1)];
        }
    #pragma unroll
    for (int i = 0; i < 4; i++)
        #pragma unroll
        for (int n = 0; n < 4; n++)
            #pragma unroll
            for (int r = 0; r < 4; r++)
                acc[i][n][r] *= sC[i][r];

    // epilogue: tile absmax -> scale, transpose via LDS, int16 store
    float mx = 0.f;
    #pragma unroll
    for (int i = 0; i < 4; i++)
        #pragma unroll
        for (int n = 0; n < 4; n++)
            #pragma unroll
            for (int r = 0; r < 4; r++)
                mx = fmaxf(mx, fabsf(acc[i][n][r]));
    #pragma unroll
    for (int off = 32; off > 0; off >>= 1)
        mx = fmaxf(mx, __shfl_xor(mx, off));
    if (lane == 0) ((float*)smem)[wid] = mx;
    __syncthreads();
    float tmax = fmaxf(fmaxf(((float*)smem)[0], ((float*)smem)[1]),
                       fmaxf(((float*)smem)[2], ((float*)smem)[3]));
    float scl = tmax * (1.0f / 32767.0f);
    float inv = (tmax > 0.f) ? (32767.0f / tmax) : 0.f;
    __syncthreads();

    float* ep = (float*)smem + wid * 4096;
    #pragma unroll
    for (int i = 0; i < 4; i++)
        #pragma unroll
        for (int n = 0; n < 4; n++)
            #pragma unroll
            for (int r = 0; r < 4; r++)
                ep[(i * 16 + kg * 4 + r) * 64 + n * 16 + r15] = acc[i][n][r];
    __syncthreads();

    int q = lane & 15;
    int rsub = lane >> 4;
    #pragma unroll
    for (int p = 0; p < 16; p++) {
        int lrow = p * 4 + rsub;
        int grow = m0 + wm * 64 + lrow;
        if (grow < M) {
            int q0 = __float2int_rn(ep[lrow * 64 + q * 4 + 0] * inv);
            int q1 = __float2int_rn(ep[lrow * 64 + q * 4 + 1] * inv);
            int q2 = __float2int_rn(ep[lrow * 64 + q * 4 + 2] * inv);
            int q3 = __float2int_rn(ep[lrow * 64 + q * 4 + 3] * inv);
            uint2 d;
            d.x = (q0 & 0xFFFF) | (q1 << 16);
            d.y = (q2 & 0xFFFF) | (q3 << 16);
            int col = n0 + wn * 64 + q * 4;
            *(uint2*)(H16 + (size_t)grow * 512 + (size_t)col * 2) = d;
        }
    }

    if (tid < GM && m0 + tid < M)
        hcomb[(size_t)(m0 + tid) * 2 + (n0 >> 7)] = scl * dis[m0 + tid];
}

// ---------------- sparse aggregation (gather-CSR over int16 H, src-only edges) --------
// out[n] = d * ( hcomb[n]*h[n] + sum_e hcomb[src_e]*h[src_e] ) + bias, d = dis[n]
// MODE 0: gelu -> per-node absmax -> int16 quantize to Xout + sxout (layers 1,2)
// MODE 1: fp32 store to out (layer 3, no gelu)

template <int MODE>
__global__ __launch_bounds__(256) void k_agg(const uint8_t* __restrict__ H16,
                                             const float* __restrict__ hcomb,
                                             const float* __restrict__ dis,
                                             const int* __restrict__ rowptr,
                                             const int* __restrict__ ssrc,
                                             const float* __restrict__ bias,
                                             float* __restrict__ out,
                                             uint8_t* __restrict__ Xout,
                                             float* __restrict__ sxout, int N) {
    int node = blockIdx.x * 4 + threadIdx.y;
    if (node >= N) return;
    int lane = threadIdx.x;  // 0..63
    int half = lane >> 5;
    float d = dis[node];
    short4 hv = *(const short4*)(H16 + (size_t)node * 512 + (size_t)lane * 8);
    float wself = d * hcomb[(size_t)node * 2 + half];   // dis^2 * hscale
    float ax = wself * (float)hv.x, ay = wself * (float)hv.y;
    float az = wself * (float)hv.z, aw = wself * (float)hv.w;
    int s = rowptr[node], e = rowptr[node + 1];
    int j = s;
    for (; j + 8 <= e; j += 8) {
        int p[8];
        #pragma unroll
        for (int t = 0; t < 8; t++) p[t] = ssrc[j + t];
        short4 v[8];
        float sc[8];
        #pragma unroll
        for (int t = 0; t < 8; t++) {
            v[t] = *(const short4*)(H16 + (size_t)p[t] * 512 + (size_t)lane * 8);
            sc[t] = hcomb[(size_t)p[t] * 2 + half];
        }
        #pragma unroll
        for (int t = 0; t < 8; t++) {
            float wn = d * sc[t];
            ax += wn * (float)v[t].x; ay += wn * (float)v[t].y;
            az += wn * (float)v[t].z; aw += wn * (float)v[t].w;
        }
    }
    for (; j < e; j++) {
        int p = ssrc[j];
        float wn = d * hcomb[(size_t)p * 2 + half];
        short4 v = *(const short4*)(H16 + (size_t)p * 512 + (size_t)lane * 8);
        ax += wn * (float)v.x; ay += wn * (float)v.y;
        az += wn * (float)v.z; aw += wn * (float)v.w;
    }
    float4 b = ((const float4*)bias)[lane];
    ax += b.x; ay += b.y; az += b.z; aw += b.w;
    if (MODE == 0) {
        ax = gelu_f(ax); ay = gelu_f(ay); az = gelu_f(az); aw = gelu_f(aw);
        float mx = fmaxf(fmaxf(fabsf(ax), fabsf(ay)), fmaxf(fabsf(az), fabsf(aw)));
        #pragma unroll
        for (int off = 32; off > 0; off >>= 1)
            mx = fmaxf(mx, __shfl_xor(mx, off));
        float inv = (mx > 0.f) ? (32767.0f / mx) : 0.f;
        short4 q;
        q.x = (short)__float2int_rn(ax * inv);
        q.y = (short)__float2int_rn(ay * inv);
        q.z = (short)__float2int_rn(az * inv);
        q.w = (short)__float2int_rn(aw * inv);
        *(short4*)(Xout + (size_t)node * 512 + (size_t)lane * 8) = q;
        if (lane == 0) sxout[node] = mx * (1.0f / 32767.0f);
    } else {
        ((float4*)(out + (size_t)node * CH))[lane] = make_float4(ax, ay, az, aw);
    }
}

// ---------------- launcher ----------------

extern "C" void kernel_launch(void* const* d_in, const int* in_sizes, int n_in,
                              void* d_out, int out_size, void* d_ws, size_t ws_size,
                              hipStream_t stream) {
    const float* x  = (const float*)d_in[0];
    const void*  ei = d_in[1];
    const float* W1 = (const float*)d_in[3]; const float* b1 = (const float*)d_in[4];
    const float* W2 = (const float*)d_in[5]; const float* b2 = (const float*)d_in[6];
    const float* W3 = (const float*)d_in[7]; const float* b3 = (const float*)d_in[8];

    int N = in_sizes[0] / CH;
    int E = in_sizes[1] / 2;
    float* out = (float*)d_out;

    char* ws = (char*)d_ws;
    auto take = [&](size_t bytes) {
        char* p = ws;
        ws += (bytes + 15) & ~(size_t)15;
        return p;
    };
    uint8_t*  H16    = (uint8_t*) take((size_t)N * 512);
    uint8_t*  Xa     = (uint8_t*) take((size_t)N * 512);
    uint8_t*  Xb     = (uint8_t*) take((size_t)N * 512);
    float*    hcomb  = (float*)   take((size_t)N * 2 * sizeof(float));
    float*    sxa    = (float*)   take((size_t)N * sizeof(float));
    float*    sxb    = (float*)   take((size_t)N * sizeof(float));
    int*      deg    = (int*)     take((size_t)N * sizeof(int));
    float*    dis    = (float*)   take((size_t)N * sizeof(float));
    int*      rowptr = (int*)     take((size_t)(N + 1) * sizeof(int));
    int*      cnt    = (int*)     take((size_t)N * sizeof(int));
    int*      part   = (int*)     take(4096);
    int*      ssrc   = (int*)     take((size_t)E * sizeof(int));
    _Float16* Wh1    = (_Float16*)take((size_t)CH * CH * 2);
    _Float16* Wh2    = (_Float16*)take((size_t)CH * CH * 2);
    _Float16* Wh3    = (_Float16*)take((size_t)CH * CH * 2);

    int eb = (E + 255) / 256;
    int nb = (N + 255) / 256;

    // fused independent prep: zero deg/cnt + weights + quant_x (one dispatch)
    k_pre<<<2048, 256, 0, stream>>>(x, W1, W2, W3, deg, cnt, Xa, sxa, Wh1, Wh2, Wh3, N);

    k_deg<<<eb, 256, 0, stream>>>(ei, deg, E);
    k_scan_block<<<nb, 256, 0, stream>>>(deg, rowptr, part, N);
    k_scan_partial<<<1, 256, 0, stream>>>(part, nb);
    k_add_off<<<nb, 256, 0, stream>>>(rowptr, part, deg, dis, N, E);
    k_scatter<<<eb, 256, 0, stream>>>(ei, rowptr, cnt, ssrc, E);

    dim3 ggrid((N + GM - 1) / GM, CH / GN);
    dim3 agrid((N + 3) / 4);
    dim3 ablock(64, 4);

    // layer 1: Xa -> H16 -> Xb
    k_gemm16<<<ggrid, 256, 0, stream>>>(Xa, sxa, Wh1, dis, H16, hcomb, N);
    k_agg<0><<<agrid, ablock, 0, stream>>>(H16, hcomb, dis, rowptr, ssrc, b1, out, Xb, sxb, N);
    // layer 2: Xb -> H16 -> Xa
    k_gemm16<<<ggrid, 256, 0, stream>>>(Xb, sxb, Wh2, dis, H16, hcomb, N);
    k_agg<0><<<agrid, ablock, 0, stream>>>(H16, hcomb, dis, rowptr, ssrc, b2, out, Xa, sxa, N);
    // layer 3: Xa -> H16 -> out (fp32, no gelu)
    k_gemm16<<<ggrid, 256, 0, stream>>>(Xa, sxa, Wh3, dis, H16, hcomb, N);
    k_agg<1><<<agrid, ablock, 0, stream>>>(H16, hcomb, dis, rowptr, ssrc, b3, out, Xb, sxb, N);
}

// Round 19
// 365.938 us; speedup vs baseline: 2.4769x; 1.0196x over previous
//
#include <hip/hip_runtime.h>
#include <cstdint>
#include <cstddef>

#define CH 256      // all layers are 256-channel

typedef _Float16 f16x8 __attribute__((ext_vector_type(8)));
typedef _Float16 f16x4 __attribute__((ext_vector_type(4)));
typedef float f32x4 __attribute__((ext_vector_type(4)));
typedef short short8 __attribute__((ext_vector_type(8)));

#define GLOB(x) ((const __attribute__((address_space(1))) void*)(x))
#define LDSP(x) ((__attribute__((address_space(3))) void*)(x))

// ---------------- helpers ----------------

__device__ __forceinline__ int ld_idx(const void* p, long long i, int w64) {
    if (w64) return (int)((const long long*)p)[i];
    return ((const int*)p)[i];
}

__device__ __forceinline__ float gelu_f(float x) {
    float x3 = x * x * x;
    float t = tanhf(0.7978845608028654f * (x + 0.044715f * x3));
    return 0.5f * x * (1.0f + t);
}

// per-block int64-vs-int32 layout detect (64 samples, L2-hot, deterministic)
__device__ __forceinline__ int detect_w64(const void* ei, int E, int* sflag) {
    int tid = threadIdx.x;
    if (tid < 64) {
        long long k = ((long long)tid * (long long)(E - 1)) / 63;
        int w = ((const int*)ei)[2 * k + 1];
        unsigned long long vote = __ballot(w == 0);
        if (tid == 0) *sflag = (vote == ~0ULL) ? 1 : 0;
    }
    __syncthreads();
    return *sflag;
}

// ---------------- fused independent preprocessing ----------------

__global__ __launch_bounds__(256)
void k_pre(const float* __restrict__ x,
           const float* __restrict__ W1, const float* __restrict__ W2,
           const float* __restrict__ W3,
           int* __restrict__ deg, int* __restrict__ cnt,
           uint8_t* __restrict__ Xa, float* __restrict__ sxa,
           _Float16* __restrict__ Wh1, _Float16* __restrict__ Wh2,
           _Float16* __restrict__ Wh3, int N) {
    const int tid   = threadIdx.x;
    const int gsize = gridDim.x * 256;
    const int gid0  = blockIdx.x * 256 + tid;

    for (int i = gid0; i < N; i += gsize) { deg[i] = 0; cnt[i] = 0; }

    for (int i = gid0; i < 3 * CH * CH; i += gsize) {   // weight transpose+cast
        int l = i >> 16;
        int r = i & 65535;
        const float* W = (l == 0) ? W1 : (l == 1) ? W2 : W3;
        _Float16*   Wh = (l == 0) ? Wh1 : (l == 1) ? Wh2 : Wh3;
        Wh[r] = (_Float16)W[(r & 255) * CH + (r >> 8)];
    }

    // quantize x: one node per wave
    int wave = gid0 >> 6, lane = tid & 63;
    int nwaves = gsize >> 6;
    for (int node = wave; node < N; node += nwaves) {
        float4 v = ((const float4*)(x + (size_t)node * CH))[lane];
        float mx = fmaxf(fmaxf(fabsf(v.x), fabsf(v.y)), fmaxf(fabsf(v.z), fabsf(v.w)));
        #pragma unroll
        for (int off = 32; off > 0; off >>= 1)
            mx = fmaxf(mx, __shfl_xor(mx, off));
        float inv = (mx > 0.f) ? (32767.0f / mx) : 0.f;
        short4 q;
        q.x = (short)__float2int_rn(v.x * inv);
        q.y = (short)__float2int_rn(v.y * inv);
        q.z = (short)__float2int_rn(v.z * inv);
        q.w = (short)__float2int_rn(v.w * inv);
        *(short4*)(Xa + (size_t)node * 512 + (size_t)lane * 8) = q;
        if (lane == 0) sxa[node] = mx * (1.0f / 32767.0f);
    }
}

// ---------------- graph preprocessing ----------------

__global__ void k_deg(const void* __restrict__ ei, int* __restrict__ deg, int E) {
    __shared__ int sflag;
    int w64 = detect_w64(ei, E, &sflag);
    int e = blockIdx.x * blockDim.x + threadIdx.x;
    if (e >= E) return;
    int d = ld_idx(ei, (long long)E + e, w64);
    atomicAdd(&deg[d], 1);
}

__global__ void k_scan_block(const int* __restrict__ deg, int* __restrict__ rowptr,
                             int* __restrict__ partial, int N) {
    __shared__ int s[256];
    int gid = blockIdx.x * 256 + threadIdx.x;
    int v = (gid < N) ? deg[gid] : 0;
    s[threadIdx.x] = v;
    __syncthreads();
    for (int off = 1; off < 256; off <<= 1) {
        int t = (threadIdx.x >= off) ? s[threadIdx.x - off] : 0;
        __syncthreads();
        s[threadIdx.x] += t;
        __syncthreads();
    }
    if (gid < N) rowptr[gid] = s[threadIdx.x] - v;
    if (threadIdx.x == 255) partial[blockIdx.x] = s[255];
}

__global__ void k_scan_partial(int* __restrict__ partial, int nb) {
    __shared__ int s[256];
    int i = threadIdx.x;
    int v = (i < nb) ? partial[i] : 0;
    s[i] = v;
    __syncthreads();
    for (int off = 1; off < 256; off <<= 1) {
        int t = (i >= off) ? s[i - off] : 0;
        __syncthreads();
        s[i] += t;
        __syncthreads();
    }
    if (i < nb) partial[i] = s[i] - v;
}

// fused: rowptr offset add + dis computation
__global__ void k_add_off(int* __restrict__ rowptr, const int* __restrict__ partial,
                          const int* __restrict__ deg, float* __restrict__ dis,
                          int N, int E) {
    int gid = blockIdx.x * 256 + threadIdx.x;
    if (gid < N) {
        rowptr[gid] += partial[blockIdx.x];
        dis[gid] = 1.0f / sqrtf((float)(deg[gid] + 1));
    }
    if (gid == 0) rowptr[N] = E;
}

// src-only scatter
__global__ void k_scatter(const void* __restrict__ ei, const int* __restrict__ rowptr,
                          int* __restrict__ cnt, int* __restrict__ ssrc, int E) {
    __shared__ int sflag;
    int w64 = detect_w64(ei, E, &sflag);
    int e = blockIdx.x * blockDim.x + threadIdx.x;
    if (e >= E) return;
    int s = ld_idx(ei, e, w64);
    int d = ld_idx(ei, (long long)E + e, w64);
    int pos = rowptr[d] + atomicAdd(&cnt[d], 1);
    ssrc[pos] = s;
}

// ---------------- GEMM (int16 A as fp16, fp16 B, late scale fold) ----------------

#define GM 128
#define GN 128
#define GK 32

__global__ __launch_bounds__(256, 2)
void k_gemm16(const uint8_t* __restrict__ X16, const float* __restrict__ sx,
              const _Float16* __restrict__ Bh, const float* __restrict__ dis,
              uint8_t* __restrict__ H16, float* __restrict__ hcomb, int M) {
    __shared__ __align__(16) char smem[65536];
    short*    lA16 = (short*)smem;              // [2][128*32] int16 = 16 KB
    _Float16* lB   = (_Float16*)(smem + 16384); // [2][128*32] f16 = 16 KB

    const int tid  = threadIdx.x;
    const int lane = tid & 63;
    const int wid  = tid >> 6;
    const int m0   = blockIdx.x * GM;
    const int n0   = blockIdx.y * GN;
    const int wm   = wid >> 1, wn = wid & 1;
    const int r15  = lane & 15, kg = lane >> 4;

    auto stage = [&](int buf, int k0) {
        #pragma unroll
        for (int c = 0; c < 4; c++) {
            int call = wid * 4 + c;                 // wave-uniform 0..15
            int cc = call & 7;
            int L = cc * 64 + lane;                 // 0..511
            int row = L >> 2, ch = L & 3;
            int sch = ch ^ ((row >> 1) & 3);        // both-sides chunk swizzle
            if (call < 8) {                         // A int16: 128 rows x 4 chunks
                int gr = m0 + row; gr = (gr < M) ? gr : (M - 1);
                const uint8_t* g = X16 + (size_t)gr * 512 + (size_t)k0 * 2 + (sch << 4);
                __builtin_amdgcn_global_load_lds(GLOB(g), LDSP(&lA16[buf * 4096 + L * 8]), 16, 0, 0);
            } else {                                // B fp16: 128 rows x 4 chunks
                const _Float16* g = Bh + (size_t)(n0 + row) * CH + k0 + (sch << 3);
                __builtin_amdgcn_global_load_lds(GLOB(g), LDSP(&lB[buf * 4096 + L * 8]), 16, 0, 0);
            }
        }
    };

    f32x4 acc[4][4];
    #pragma unroll
    for (int i = 0; i < 4; i++)
        #pragma unroll
        for (int n = 0; n < 4; n++)
            acc[i][n] = (f32x4){0.f, 0.f, 0.f, 0.f};

    stage(0, 0);
    __syncthreads();

    for (int ks = 0; ks < 8; ks++) {
        int cur = ks & 1;
        if (ks < 7) stage(cur ^ 1, (ks + 1) * GK);

        f16x8 aq[4], bh[4];
        #pragma unroll
        for (int i = 0; i < 4; i++) {
            int R = wm * 64 + i * 16 + r15;
            int p = kg ^ ((R >> 1) & 3);
            short8 q = *(const short8*)&lA16[cur * 4096 + R * 32 + p * 8];
            #pragma unroll
            for (int j = 0; j < 8; j++)
                aq[i][j] = (_Float16)q[j];
        }
        #pragma unroll
        for (int n = 0; n < 4; n++) {
            int C = wn * 64 + n * 16 + r15;
            int p = kg ^ ((C >> 1) & 3);
            bh[n] = *(const f16x8*)&lB[cur * 4096 + C * GK + p * 8];
        }
        #pragma unroll
        for (int i = 0; i < 4; i++)
            #pragma unroll
            for (int n = 0; n < 4; n++)
                acc[i][n] = __builtin_amdgcn_mfma_f32_16x16x32_f16(aq[i], bh[n], acc[i][n], 0, 0, 0);
        __syncthreads();
    }

    // fold row-uniform input scale
    float sC[4][4];
    #pragma unroll
    for (int i = 0; i < 4; i++)
        #pragma unroll
        for (int r = 0; r < 4; r++) {
            int gr = m0 + wm * 64 + i * 16 + kg * 4 + r;
            sC[i][r] = sx[(gr < M) ? gr : (M - 1)];
        }
    #pragma unroll
    for (int i = 0; i < 4; i++)
        #pragma unroll
        for (int n = 0; n < 4; n++)
            #pragma unroll
            for (int r = 0; r < 4; r++)
                acc[i][n][r] *= sC[i][r];

    // epilogue: tile absmax -> scale, transpose via LDS, int16 store
    float mx = 0.f;
    #pragma unroll
    for (int i = 0; i < 4; i++)
        #pragma unroll
        for (int n = 0; n < 4; n++)
            #pragma unroll
            for (int r = 0; r < 4; r++)
                mx = fmaxf(mx, fabsf(acc[i][n][r]));
    #pragma unroll
    for (int off = 32; off > 0; off >>= 1)
        mx = fmaxf(mx, __shfl_xor(mx, off));
    if (lane == 0) ((float*)smem)[wid] = mx;
    __syncthreads();
    float tmax = fmaxf(fmaxf(((float*)smem)[0], ((float*)smem)[1]),
                       fmaxf(((float*)smem)[2], ((float*)smem)[3]));
    float scl = tmax * (1.0f / 32767.0f);
    float inv = (tmax > 0.f) ? (32767.0f / tmax) : 0.f;
    __syncthreads();

    float* ep = (float*)smem + wid * 4096;
    #pragma unroll
    for (int i = 0; i < 4; i++)
        #pragma unroll
        for (int n = 0; n < 4; n++)
            #pragma unroll
            for (int r = 0; r < 4; r++)
                ep[(i * 16 + kg * 4 + r) * 64 + n * 16 + r15] = acc[i][n][r];
    __syncthreads();

    int q = lane & 15;
    int rsub = lane >> 4;
    #pragma unroll
    for (int p = 0; p < 16; p++) {
        int lrow = p * 4 + rsub;
        int grow = m0 + wm * 64 + lrow;
        if (grow < M) {
            int q0 = __float2int_rn(ep[lrow * 64 + q * 4 + 0] * inv);
            int q1 = __float2int_rn(ep[lrow * 64 + q * 4 + 1] * inv);
            int q2 = __float2int_rn(ep[lrow * 64 + q * 4 + 2] * inv);
            int q3 = __float2int_rn(ep[lrow * 64 + q * 4 + 3] * inv);
            uint2 d;
            d.x = (q0 & 0xFFFF) | (q1 << 16);
            d.y = (q2 & 0xFFFF) | (q3 << 16);
            int col = n0 + wn * 64 + q * 4;
            *(uint2*)(H16 + (size_t)grow * 512 + (size_t)col * 2) = d;
        }
    }

    if (tid < GM && m0 + tid < M)
        hcomb[(size_t)(m0 + tid) * 2 + (n0 >> 7)] = scl * dis[m0 + tid];
}

// ---------------- sparse aggregation: 8 ch/lane, 32 lanes/node, 2 nodes/wave --------
// out[n] = d * ( hcomb[n]*h[n] + sum_e hcomb[src_e]*h[src_e] ) + bias, d = dis[n]
// MODE 0: gelu -> per-node absmax -> int16 quantize to Xout + sxout (layers 1,2)
// MODE 1: fp32 store to out (layer 3, no gelu)

template <int MODE>
__global__ __launch_bounds__(256) void k_agg(const uint8_t* __restrict__ H16,
                                             const float* __restrict__ hcomb,
                                             const float* __restrict__ dis,
                                             const int* __restrict__ rowptr,
                                             const int* __restrict__ ssrc,
                                             const float* __restrict__ bias,
                                             float* __restrict__ out,
                                             uint8_t* __restrict__ Xout,
                                             float* __restrict__ sxout, int N) {
    int lane = threadIdx.x;                      // 0..63
    int sub  = lane >> 5;                        // node within wave pair
    int node = blockIdx.x * 8 + threadIdx.y * 2 + sub;
    if (node >= N) return;
    int cl   = lane & 31;                        // channel lane: ch cl*8 .. cl*8+7
    int half = cl >> 4;                          // 0: ch<128, 1: ch>=128
    float d = dis[node];

    short8 hv = *(const short8*)(H16 + (size_t)node * 512 + (size_t)cl * 16);
    float wself = d * hcomb[(size_t)node * 2 + half];
    float a[8];
    #pragma unroll
    for (int k = 0; k < 8; k++) a[k] = wself * (float)hv[k];

    int s = rowptr[node], e = rowptr[node + 1];
    int j = s;
    for (; j + 4 <= e; j += 4) {
        int p[4];
        #pragma unroll
        for (int t = 0; t < 4; t++) p[t] = ssrc[j + t];
        short8 v[4];
        float sc[4];
        #pragma unroll
        for (int t = 0; t < 4; t++) {
            v[t] = *(const short8*)(H16 + (size_t)p[t] * 512 + (size_t)cl * 16);
            sc[t] = hcomb[(size_t)p[t] * 2 + half];
        }
        #pragma unroll
        for (int t = 0; t < 4; t++) {
            float wn = d * sc[t];
            #pragma unroll
            for (int k = 0; k < 8; k++) a[k] += wn * (float)v[t][k];
        }
    }
    for (; j < e; j++) {
        int p = ssrc[j];
        float wn = d * hcomb[(size_t)p * 2 + half];
        short8 v = *(const short8*)(H16 + (size_t)p * 512 + (size_t)cl * 16);
        #pragma unroll
        for (int k = 0; k < 8; k++) a[k] += wn * (float)v[k];
    }

    float4 b0 = ((const float4*)bias)[cl * 2];
    float4 b1 = ((const float4*)bias)[cl * 2 + 1];
    a[0] += b0.x; a[1] += b0.y; a[2] += b0.z; a[3] += b0.w;
    a[4] += b1.x; a[5] += b1.y; a[6] += b1.z; a[7] += b1.w;

    if (MODE == 0) {
        #pragma unroll
        for (int k = 0; k < 8; k++) a[k] = gelu_f(a[k]);
        float mx = 0.f;
        #pragma unroll
        for (int k = 0; k < 8; k++) mx = fmaxf(mx, fabsf(a[k]));
        #pragma unroll
        for (int off = 16; off > 0; off >>= 1)
            mx = fmaxf(mx, __shfl_xor(mx, off, 32));   // reduce within 32-lane group
        float inv = (mx > 0.f) ? (32767.0f / mx) : 0.f;
        short8 q;
        #pragma unroll
        for (int k = 0; k < 8; k++) q[k] = (short)__float2int_rn(a[k] * inv);
        *(short8*)(Xout + (size_t)node * 512 + (size_t)cl * 16) = q;
        if (cl == 0) sxout[node] = mx * (1.0f / 32767.0f);
    } else {
        float* o = out + (size_t)node * CH + cl * 8;
        *(f32x4*)o       = (f32x4){a[0], a[1], a[2], a[3]};
        *(f32x4*)(o + 4) = (f32x4){a[4], a[5], a[6], a[7]};
    }
}

// ---------------- launcher ----------------

extern "C" void kernel_launch(void* const* d_in, const int* in_sizes, int n_in,
                              void* d_out, int out_size, void* d_ws, size_t ws_size,
                              hipStream_t stream) {
    const float* x  = (const float*)d_in[0];
    const void*  ei = d_in[1];
    const float* W1 = (const float*)d_in[3]; const float* b1 = (const float*)d_in[4];
    const float* W2 = (const float*)d_in[5]; const float* b2 = (const float*)d_in[6];
    const float* W3 = (const float*)d_in[7]; const float* b3 = (const float*)d_in[8];

    int N = in_sizes[0] / CH;
    int E = in_sizes[1] / 2;
    float* out = (float*)d_out;

    char* ws = (char*)d_ws;
    auto take = [&](size_t bytes) {
        char* p = ws;
        ws += (bytes + 15) & ~(size_t)15;
        return p;
    };
    uint8_t*  H16    = (uint8_t*) take((size_t)N * 512);
    uint8_t*  Xa     = (uint8_t*) take((size_t)N * 512);
    uint8_t*  Xb     = (uint8_t*) take((size_t)N * 512);
    float*    hcomb  = (float*)   take((size_t)N * 2 * sizeof(float));
    float*    sxa    = (float*)   take((size_t)N * sizeof(float));
    float*    sxb    = (float*)   take((size_t)N * sizeof(float));
    int*      deg    = (int*)     take((size_t)N * sizeof(int));
    float*    dis    = (float*)   take((size_t)N * sizeof(float));
    int*      rowptr = (int*)     take((size_t)(N + 1) * sizeof(int));
    int*      cnt    = (int*)     take((size_t)N * sizeof(int));
    int*      part   = (int*)     take(4096);
    int*      ssrc   = (int*)     take((size_t)E * sizeof(int));
    _Float16* Wh1    = (_Float16*)take((size_t)CH * CH * 2);
    _Float16* Wh2    = (_Float16*)take((size_t)CH * CH * 2);
    _Float16* Wh3    = (_Float16*)take((size_t)CH * CH * 2);

    int eb = (E + 255) / 256;
    int nb = (N + 255) / 256;

    // fused independent prep: zero deg/cnt + weights + quant_x (one dispatch)
    k_pre<<<2048, 256, 0, stream>>>(x, W1, W2, W3, deg, cnt, Xa, sxa, Wh1, Wh2, Wh3, N);

    k_deg<<<eb, 256, 0, stream>>>(ei, deg, E);
    k_scan_block<<<nb, 256, 0, stream>>>(deg, rowptr, part, N);
    k_scan_partial<<<1, 256, 0, stream>>>(part, nb);
    k_add_off<<<nb, 256, 0, stream>>>(rowptr, part, deg, dis, N, E);
    k_scatter<<<eb, 256, 0, stream>>>(ei, rowptr, cnt, ssrc, E);

    dim3 ggrid((N + GM - 1) / GM, CH / GN);
    dim3 agrid((N + 7) / 8);
    dim3 ablock(64, 4);

    // layer 1: Xa -> H16 -> Xb
    k_gemm16<<<ggrid, 256, 0, stream>>>(Xa, sxa, Wh1, dis, H16, hcomb, N);
    k_agg<0><<<agrid, ablock, 0, stream>>>(H16, hcomb, dis, rowptr, ssrc, b1, out, Xb, sxb, N);
    // layer 2: Xb -> H16 -> Xa
    k_gemm16<<<ggrid, 256, 0, stream>>>(Xb, sxb, Wh2, dis, H16, hcomb, N);
    k_agg<0><<<agrid, ablock, 0, stream>>>(H16, hcomb, dis, rowptr, ssrc, b2, out, Xa, sxa, N);
    // layer 3: Xa -> H16 -> out (fp32, no gelu)
    k_gemm16<<<ggrid, 256, 0, stream>>>(Xa, sxa, Wh3, dis, H16, hcomb, N);
    k_agg<1><<<agrid, ablock, 0, stream>>>(H16, hcomb, dis, rowptr, ssrc, b3, out, Xb, sxb, N);
}